// Round 5
// baseline (120.303 us; speedup 1.0000x reference)
//
#include <hip/hip_runtime.h>
#include <math.h>

// knnLoss: B=4, N=8192, k=3. Brute-force 3-NN, single fused kernel.
// R5: R4 fusion + restored occupancy (the R4 regression was 8 waves/CU).
//   - 1024 blocks x 256 threads (4 blocks/CU, 16 waves/CU = R3-partial's
//     geometry, which measured VALUBusy 68%).
//   - Block owns 32 sources. Wave w processes staged slot w; within a wave,
//     lanes<32 handle octets 0..31 and lanes>=32 handle octets 32..63 of the
//     slot (2 distinct ds_read addrs/wave = free 2-way aliasing).
//   - Octet-min selection (packed 5-bit index) + per-round exact fixup before
//     the LDS slot is overwritten. Exactness: global top-3 value => top-3 of
//     its (round,slot,half) group => its octet is a top-3 octet-min there =>
//     exact value re-inserted by fixup.
//   - Final: 8 exact triples per source (4 waves x 2 halves) merged via LDS,
//     32-lane shuffle reduce, per-block atomics + ticket finale.
#define BATCH 4
#define NPTS 8192
#define TILE 512
#define SLOTS 4               // tiles staged per round (one per wave)
#define ROUNDS 4              // 16 tiles / 4 slots
#define SRC_PER_BLOCK 32
#define NBLOCKS (BATCH * NPTS / SRC_PER_BLOCK)  // 1024
#define NOCT 64               // octets per tile
#define OCTF 36               // floats per padded octet (9 float4 = 144 B)
#define SLOTF (NOCT * OCTF)   // 2304 floats per LDS slot

typedef __attribute__((ext_vector_type(2))) float f2;

__device__ __forceinline__ float min3f(float a, float b, float c) {
    float d;
    asm("v_min3_f32 %0, %1, %2, %3" : "=v"(d) : "v"(a), "v"(b), "v"(c));
    return d;
}

// Branchless insert into sorted ascending triple; 4 ops via med3.
__device__ __forceinline__ void insert3(float d, float& a0, float& a1, float& a2) {
    float h = fmaxf(a1, d);
    float m = __builtin_amdgcn_fmed3f(a0, a1, d);
    a2 = fminf(a2, h);
    a1 = m;
    a0 = fminf(a0, d);
}

// Merge two sorted-ascending triples -> the sorted 3 smallest of the union.
__device__ __forceinline__ void merge33(float a0, float a1, float a2,
                                        float& b0, float& b1, float& b2) {
    float s0 = fminf(a0, b0);
    float h  = fmaxf(a0, b0);
    float m  = fminf(a1, b1);
    float mm = fminf(a2, b2);
    b1 = fminf(h, m);
    b2 = __builtin_amdgcn_fmed3f(h, m, mm);
    b0 = s0;
}

// Recompute the 8 exact p-values of one octet, insert into the exact chain.
__device__ __forceinline__ void octet_insert(const float4* ob, f2 nx, f2 ny, f2 nz,
                                             float& c0, float& c1, float& c2) {
    float4 X0 = ob[0], X1 = ob[1], Y0 = ob[2], Y1 = ob[3];
    float4 Z0 = ob[4], Z1 = ob[5], W0 = ob[6], W1 = ob[7];
    f2 pa = __builtin_elementwise_fma((f2){Z0.x, Z0.y}, nz, (f2){W0.x, W0.y});
    pa = __builtin_elementwise_fma((f2){Y0.x, Y0.y}, ny, pa);
    pa = __builtin_elementwise_fma((f2){X0.x, X0.y}, nx, pa);
    f2 pb = __builtin_elementwise_fma((f2){Z0.z, Z0.w}, nz, (f2){W0.z, W0.w});
    pb = __builtin_elementwise_fma((f2){Y0.z, Y0.w}, ny, pb);
    pb = __builtin_elementwise_fma((f2){X0.z, X0.w}, nx, pb);
    f2 pc = __builtin_elementwise_fma((f2){Z1.x, Z1.y}, nz, (f2){W1.x, W1.y});
    pc = __builtin_elementwise_fma((f2){Y1.x, Y1.y}, ny, pc);
    pc = __builtin_elementwise_fma((f2){X1.x, X1.y}, nx, pc);
    f2 pd = __builtin_elementwise_fma((f2){Z1.z, Z1.w}, nz, (f2){W1.z, W1.w});
    pd = __builtin_elementwise_fma((f2){Y1.z, Y1.w}, ny, pd);
    pd = __builtin_elementwise_fma((f2){X1.z, X1.w}, nx, pd);
    insert3(pa.x, c0, c1, c2);
    insert3(pa.y, c0, c1, c2);
    insert3(pb.x, c0, c1, c2);
    insert3(pb.y, c0, c1, c2);
    insert3(pc.x, c0, c1, c2);
    insert3(pc.y, c0, c1, c2);
    insert3(pd.x, c0, c1, c2);
    insert3(pd.y, c0, c1, c2);
}

__global__ __launch_bounds__(256, 4) void knn_fused(const float* __restrict__ src,
                                                    const float* __restrict__ tgt,
                                                    float* __restrict__ acc,
                                                    float* __restrict__ cnt,
                                                    unsigned* __restrict__ ticket,
                                                    float* __restrict__ out) {
    __shared__ float tsf[SLOTS * SLOTF];  // 36864 B -> 4 blocks/CU
    const int tid = threadIdx.x;
    const int lane = tid & 63, wave = tid >> 6;
    const int slane = lane & 31;   // source lane 0..31
    const int half = lane >> 5;    // octet half 0/1
    const int bid = blockIdx.x;
    const int gid = bid * SRC_PER_BLOCK + slane;  // flat source id (b*N + i)
    const int b = bid >> 8;                       // 256 blocks per batch

    // Source precompute (8x redundant per block; trivial, L1-hits).
    const float* sp = src + (size_t)gid * 3;
    float ax = sp[0], ay = sp[1], az = sp[2];
    f2 nx = (f2){-2.f * ax, -2.f * ax};
    f2 ny = (f2){-2.f * ay, -2.f * ay};
    f2 nz = (f2){-2.f * az, -2.f * az};

    float e0 = 3e38f, e1 = 3e38f, e2 = 3e38f;  // running exact triple (p-space)

    for (int r = 0; r < ROUNDS; ++r) {
        __syncthreads();  // prior round's LDS reads complete before overwrite
        // Stage 4 tiles = 2048 targets = 1024 pairs; pair p = j*256 + tid.
        #pragma unroll
        for (int j = 0; j < 4; ++j) {
            int p = j * 256 + tid;
            const float2* tb2 = (const float2*)(tgt +
                ((size_t)b * NPTS + r * (SLOTS * TILE) + 2 * p) * 3);
            float2 A = tb2[0], Bv = tb2[1], C = tb2[2];
            float x0 = A.x, y0 = A.y, z0 = Bv.x;
            float x1 = Bv.y, y1 = C.x, z1 = C.y;
            float w0 = x0 * x0 + y0 * y0 + z0 * z0;
            float w1 = x1 * x1 + y1 * y1 + z1 * z1;
            if (!(x0 != 0.f || y0 != 0.f || z0 != 0.f)) w0 = 3.0e38f;
            if (!(x1 != 0.f || y1 != 0.f || z1 != 0.f)) w1 = 3.0e38f;
            int sl = p >> 8;           // LDS slot 0..3
            int o = (p >> 2) & 63;     // octet within tile
            int k = (2 * p) & 7;       // slot pair within octet
            int base = sl * SLOTF + o * OCTF + ((k >> 2) << 2) + (k & 3);
            *(float2*)(tsf + base)      = make_float2(x0, x1);
            *(float2*)(tsf + base + 8)  = make_float2(y0, y1);
            *(float2*)(tsf + base + 16) = make_float2(z0, z1);
            *(float2*)(tsf + base + 24) = make_float2(w0, w1);
        }
        __syncthreads();

        // Wave w -> slot w; lane half -> octets half*32 .. half*32+31.
        const float4* tsv = (const float4*)(tsf + wave * SLOTF) + 9 * 32 * half;
        float q0 = 3e38f, q1 = 3e38f, q2 = 3e38f;  // packed (min | 5-bit idx)
        #pragma unroll 2
        for (int j = 0; j < 32; ++j) {
            float4 X0 = tsv[9 * j + 0], X1 = tsv[9 * j + 1];
            float4 Y0 = tsv[9 * j + 2], Y1 = tsv[9 * j + 3];
            float4 Z0 = tsv[9 * j + 4], Z1 = tsv[9 * j + 5];
            float4 W0 = tsv[9 * j + 6], W1 = tsv[9 * j + 7];
            f2 pa = __builtin_elementwise_fma((f2){Z0.x, Z0.y}, nz, (f2){W0.x, W0.y});
            pa = __builtin_elementwise_fma((f2){Y0.x, Y0.y}, ny, pa);
            pa = __builtin_elementwise_fma((f2){X0.x, X0.y}, nx, pa);
            f2 pb = __builtin_elementwise_fma((f2){Z0.z, Z0.w}, nz, (f2){W0.z, W0.w});
            pb = __builtin_elementwise_fma((f2){Y0.z, Y0.w}, ny, pb);
            pb = __builtin_elementwise_fma((f2){X0.z, X0.w}, nx, pb);
            f2 pc = __builtin_elementwise_fma((f2){Z1.x, Z1.y}, nz, (f2){W1.x, W1.y});
            pc = __builtin_elementwise_fma((f2){Y1.x, Y1.y}, ny, pc);
            pc = __builtin_elementwise_fma((f2){X1.x, X1.y}, nx, pc);
            f2 pd = __builtin_elementwise_fma((f2){Z1.z, Z1.w}, nz, (f2){W1.z, W1.w});
            pd = __builtin_elementwise_fma((f2){Y1.z, Y1.w}, ny, pd);
            pd = __builtin_elementwise_fma((f2){X1.z, X1.w}, nx, pd);
            float m1 = min3f(pa.x, pa.y, pb.x);
            float m2 = min3f(pb.y, pc.x, pc.y);
            float m3 = min3f(pd.x, pd.y, m1);
            float m4 = fminf(m2, m3);
            unsigned u = (__float_as_uint(m4) & 0xFFFFFFE0u) | (unsigned)j;
            insert3(__uint_as_float(u), q0, q1, q2);
        }
        // Exact fixup of the <=3 candidate octets (before slot overwrite).
        octet_insert(tsv + 9 * (int)(__float_as_uint(q0) & 31u), nx, ny, nz, e0, e1, e2);
        octet_insert(tsv + 9 * (int)(__float_as_uint(q1) & 31u), nx, ny, nz, e0, e1, e2);
        octet_insert(tsv + 9 * (int)(__float_as_uint(q2) & 31u), nx, ny, nz, e0, e1, e2);
    }

    // Merge 8 chains per source (4 waves x 2 halves) via LDS (reuse tsf).
    __syncthreads();
    int chain = (wave * 2 + half) * 32 + slane;  // 0..255
    tsf[chain]       = e0;
    tsf[256 + chain] = e1;
    tsf[512 + chain] = e2;
    __syncthreads();

    if (tid < 32) {
        float a0 = tsf[tid], a1 = tsf[256 + tid], a2 = tsf[512 + tid];
        #pragma unroll
        for (int g = 1; g < 8; ++g)
            merge33(tsf[g * 32 + tid], tsf[256 + g * 32 + tid],
                    tsf[512 + g * 32 + tid], a0, a1, a2);

        bool valid = (ax != 0.f) || (ay != 0.f) || (az != 0.f);
        float qq = ax * ax + ay * ay + az * az;  // deferred |s|^2
        float s = valid ? (sqrtf(fmaxf(a0 + qq, 0.f)) + sqrtf(fmaxf(a1 + qq, 0.f)) +
                           sqrtf(fmaxf(a2 + qq, 0.f)))
                        : 0.f;
        float c = valid ? 1.f : 0.f;

        // Reduce over lanes 0..31 (garbage from >=32 never mixes in).
        for (int off = 16; off >= 1; off >>= 1) {
            s += __shfl_down(s, off);
            c += __shfl_down(c, off);
        }
        if (tid == 0) {
            atomicAdd(&acc[b], s);
            atomicAdd(&cnt[b], c);
            __threadfence();
            unsigned t = atomicAdd(ticket, 1u);
            if (t == (unsigned)(NBLOCKS - 1)) {
                float loss = 0.f;
                #pragma unroll
                for (int bb = 0; bb < BATCH; ++bb) {
                    float as = atomicAdd(&acc[bb], 0.f);
                    float ac = atomicAdd(&cnt[bb], 0.f);
                    loss += as / (ac * 3.0f);
                }
                out[0] = loss * (1.0f / BATCH);
            }
        }
    }
}

extern "C" void kernel_launch(void* const* d_in, const int* in_sizes, int n_in,
                              void* d_out, int out_size, void* d_ws, size_t ws_size,
                              hipStream_t stream) {
    const float* src = (const float*)d_in[0];
    const float* tgt = (const float*)d_in[1];
    float* out = (float*)d_out;

    // ws header: [0,16) acc[4]; [16,32) cnt[4]; [32,36) ticket
    float* acc = (float*)d_ws;
    float* cnt = acc + 4;
    unsigned* ticket = (unsigned*)((char*)d_ws + 32);

    hipMemsetAsync(d_ws, 0, 64, stream);  // zero header (graph-capturable)
    knn_fused<<<dim3(NBLOCKS), 256, 0, stream>>>(src, tgt, acc, cnt, ticket, out);
}

// Round 6
// 113.244 us; speedup vs baseline: 1.0623x; 1.0623x over previous
//
#include <hip/hip_runtime.h>
#include <math.h>

// knnLoss: B=4, N=8192, k=3. Brute-force 3-NN, single fused kernel.
// R6: LDS-throughput fix. R4/R5 were LDS-pipe bound (S=1 doubled ds_read per
// octet-eval vs R3's 2-sources-per-thread amortization; R5's half-split added
// a 2nd read address). New shape:
//   - 256 blocks x 1024 threads (16 waves). Wave w stages tile w into its OWN
//     8KB LDS slot and reads only that slot -> NO barriers in the main body
//     (wave-local LDS ordering via lgkmcnt). LDS = 128 KiB total.
//   - Each lane owns 2 sources => octet's 8 ds_read_b128 amortized over 2
//     evals (R3 ratio) + 2 independent insert3 chains (ILP).
//   - Unpadded octets (OCTF=32): broadcast reads are single-address => no
//     read conflicts regardless of alignment.
//   - Octet-min selection (6-bit packed index) + per-source exact fixup
//     (<=3 octets recomputed) => bit-exact values, selection-only packing.
//   - Tail: 1 barrier, triples to LDS, 2 waves merge 16 triples/source,
//     shuffle reduce, per-block atomics + ticket finale.
#define BATCH 4
#define NPTS 8192
#define TILE 512
#define NWAVES 16             // = NPTS / TILE tiles, one per wave
#define SRC_PER_BLOCK 128     // 64 lanes x 2 sources
#define NBLOCKS (BATCH * NPTS / SRC_PER_BLOCK)  // 256
#define NOCT 64               // octets per tile
#define OCTF 32               // floats per octet, unpadded
#define SLOTF (NOCT * OCTF)   // 2048 floats = 8 KiB per wave slot

typedef __attribute__((ext_vector_type(2))) float f2;

__device__ __forceinline__ float min3f(float a, float b, float c) {
    float d;
    asm("v_min3_f32 %0, %1, %2, %3" : "=v"(d) : "v"(a), "v"(b), "v"(c));
    return d;
}

// Branchless insert into sorted ascending triple; 4 ops via med3.
__device__ __forceinline__ void insert3(float d, float& a0, float& a1, float& a2) {
    float h = fmaxf(a1, d);
    float m = __builtin_amdgcn_fmed3f(a0, a1, d);
    a2 = fminf(a2, h);
    a1 = m;
    a0 = fminf(a0, d);
}

// Merge two sorted-ascending triples -> the sorted 3 smallest of the union.
__device__ __forceinline__ void merge33(float a0, float a1, float a2,
                                        float& b0, float& b1, float& b2) {
    float s0 = fminf(a0, b0);
    float h  = fmaxf(a0, b0);
    float m  = fminf(a1, b1);
    float mm = fminf(a2, b2);
    b1 = fminf(h, m);
    b2 = __builtin_amdgcn_fmed3f(h, m, mm);
    b0 = s0;
}

// Recompute the 8 exact p-values of one octet (8 float4s), insert into chain.
__device__ __forceinline__ void octet_insert(const float4* ob, f2 nx, f2 ny, f2 nz,
                                             float& c0, float& c1, float& c2) {
    float4 X0 = ob[0], X1 = ob[1], Y0 = ob[2], Y1 = ob[3];
    float4 Z0 = ob[4], Z1 = ob[5], W0 = ob[6], W1 = ob[7];
    f2 pa = __builtin_elementwise_fma((f2){Z0.x, Z0.y}, nz, (f2){W0.x, W0.y});
    pa = __builtin_elementwise_fma((f2){Y0.x, Y0.y}, ny, pa);
    pa = __builtin_elementwise_fma((f2){X0.x, X0.y}, nx, pa);
    f2 pb = __builtin_elementwise_fma((f2){Z0.z, Z0.w}, nz, (f2){W0.z, W0.w});
    pb = __builtin_elementwise_fma((f2){Y0.z, Y0.w}, ny, pb);
    pb = __builtin_elementwise_fma((f2){X0.z, X0.w}, nx, pb);
    f2 pc = __builtin_elementwise_fma((f2){Z1.x, Z1.y}, nz, (f2){W1.x, W1.y});
    pc = __builtin_elementwise_fma((f2){Y1.x, Y1.y}, ny, pc);
    pc = __builtin_elementwise_fma((f2){X1.x, X1.y}, nx, pc);
    f2 pd = __builtin_elementwise_fma((f2){Z1.z, Z1.w}, nz, (f2){W1.z, W1.w});
    pd = __builtin_elementwise_fma((f2){Y1.z, Y1.w}, ny, pd);
    pd = __builtin_elementwise_fma((f2){X1.z, X1.w}, nx, pd);
    insert3(pa.x, c0, c1, c2);
    insert3(pa.y, c0, c1, c2);
    insert3(pb.x, c0, c1, c2);
    insert3(pb.y, c0, c1, c2);
    insert3(pc.x, c0, c1, c2);
    insert3(pc.y, c0, c1, c2);
    insert3(pd.x, c0, c1, c2);
    insert3(pd.y, c0, c1, c2);
}

__global__ __launch_bounds__(1024, 4) void knn_fused(const float* __restrict__ src,
                                                     const float* __restrict__ tgt,
                                                     float* __restrict__ acc,
                                                     float* __restrict__ cnt,
                                                     unsigned* __restrict__ ticket,
                                                     float* __restrict__ out) {
    __shared__ float tsf[NWAVES * SLOTF];  // 131072 B -> 1 block/CU, 16 waves/CU
    const int tid = threadIdx.x;
    const int lane = tid & 63, wave = tid >> 6;
    const int bid = blockIdx.x;
    const int b = bid >> 6;  // 64 blocks per batch, uniform per block

    // Source precompute: lane owns sources bid*128 + lane and +64.
    f2 nx[2], ny[2], nz[2];
    #pragma unroll
    for (int s = 0; s < 2; ++s) {
        const float* sp = src + ((size_t)bid * SRC_PER_BLOCK + 64 * s + lane) * 3;
        float ax = sp[0], ay = sp[1], az = sp[2];
        nx[s] = (f2){-2.f * ax, -2.f * ax};
        ny[s] = (f2){-2.f * ay, -2.f * ay};
        nz[s] = (f2){-2.f * az, -2.f * az};
    }

    // Stage: wave w loads tile w into its own slot. Octet layout (32 floats):
    // x0..x7 | y0..y7 | z0..z7 | w0..w7  (float4 r: 0=x03,1=x47,2=y03,...,7=w47)
    {
        const float* tb = tgt + ((size_t)b * NPTS + wave * TILE) * 3;
        #pragma unroll
        for (int j = 0; j < 4; ++j) {
            int p = j * 64 + lane;  // pair 0..255 (targets 2p, 2p+1)
            const float2* t2 = (const float2*)(tb + 6 * p);
            float2 A = t2[0], Bv = t2[1], C = t2[2];
            float x0 = A.x, y0 = A.y, z0 = Bv.x;
            float x1 = Bv.y, y1 = C.x, z1 = C.y;
            float w0 = x0 * x0 + y0 * y0 + z0 * z0;
            float w1 = x1 * x1 + y1 * y1 + z1 * z1;
            if (!(x0 != 0.f || y0 != 0.f || z0 != 0.f)) w0 = 3.0e38f;
            if (!(x1 != 0.f || y1 != 0.f || z1 != 0.f)) w1 = 3.0e38f;
            int o = p >> 2, k = (2 * p) & 7;
            float* bp = tsf + wave * SLOTF + o * OCTF + k;
            *(float2*)(bp)      = make_float2(x0, x1);
            *(float2*)(bp + 8)  = make_float2(y0, y1);
            *(float2*)(bp + 16) = make_float2(z0, z1);
            *(float2*)(bp + 24) = make_float2(w0, w1);
        }
    }
    // No __syncthreads: this wave reads only the slot it wrote (lgkmcnt orders).

    // Hot loop: 64 octets x 2 sources; 8 broadcast ds_read_b128 per octet.
    float q0[2], q1[2], q2c[2];
    #pragma unroll
    for (int s = 0; s < 2; ++s) { q0[s] = q1[s] = q2c[s] = 3e38f; }

    const float4* tsv = (const float4*)(tsf + wave * SLOTF);
    #pragma unroll 2
    for (int j = 0; j < NOCT; ++j) {
        float4 X0 = tsv[8 * j + 0], X1 = tsv[8 * j + 1];
        float4 Y0 = tsv[8 * j + 2], Y1 = tsv[8 * j + 3];
        float4 Z0 = tsv[8 * j + 4], Z1 = tsv[8 * j + 5];
        float4 W0 = tsv[8 * j + 6], W1 = tsv[8 * j + 7];
        #pragma unroll
        for (int s = 0; s < 2; ++s) {
            f2 pa = __builtin_elementwise_fma((f2){Z0.x, Z0.y}, nz[s], (f2){W0.x, W0.y});
            pa = __builtin_elementwise_fma((f2){Y0.x, Y0.y}, ny[s], pa);
            pa = __builtin_elementwise_fma((f2){X0.x, X0.y}, nx[s], pa);
            f2 pb = __builtin_elementwise_fma((f2){Z0.z, Z0.w}, nz[s], (f2){W0.z, W0.w});
            pb = __builtin_elementwise_fma((f2){Y0.z, Y0.w}, ny[s], pb);
            pb = __builtin_elementwise_fma((f2){X0.z, X0.w}, nx[s], pb);
            f2 pc = __builtin_elementwise_fma((f2){Z1.x, Z1.y}, nz[s], (f2){W1.x, W1.y});
            pc = __builtin_elementwise_fma((f2){Y1.x, Y1.y}, ny[s], pc);
            pc = __builtin_elementwise_fma((f2){X1.x, X1.y}, nx[s], pc);
            f2 pd = __builtin_elementwise_fma((f2){Z1.z, Z1.w}, nz[s], (f2){W1.z, W1.w});
            pd = __builtin_elementwise_fma((f2){Y1.z, Y1.w}, ny[s], pd);
            pd = __builtin_elementwise_fma((f2){X1.z, X1.w}, nx[s], pd);
            float m1 = min3f(pa.x, pa.y, pb.x);
            float m2 = min3f(pb.y, pc.x, pc.y);
            float m3 = min3f(pd.x, pd.y, m1);
            float m4 = fminf(m2, m3);
            unsigned u = (__float_as_uint(m4) & 0xFFFFFFC0u) | (unsigned)j;
            insert3(__uint_as_float(u), q0[s], q1[s], q2c[s]);
        }
    }

    // Exact fixup: recompute the <=3 candidate octets per source.
    float e0[2], e1[2], e2[2];
    #pragma unroll
    for (int s = 0; s < 2; ++s) {
        e0[s] = 3e38f; e1[s] = 3e38f; e2[s] = 3e38f;
        octet_insert(tsv + 8 * (int)(__float_as_uint(q0[s]) & 63u),
                     nx[s], ny[s], nz[s], e0[s], e1[s], e2[s]);
        octet_insert(tsv + 8 * (int)(__float_as_uint(q1[s]) & 63u),
                     nx[s], ny[s], nz[s], e0[s], e1[s], e2[s]);
        octet_insert(tsv + 8 * (int)(__float_as_uint(q2c[s]) & 63u),
                     nx[s], ny[s], nz[s], e0[s], e1[s], e2[s]);
    }

    // All waves must finish reading their slots before triples reuse the LDS.
    __syncthreads();
    #pragma unroll
    for (int s = 0; s < 2; ++s) {
        int base = ((wave * 2 + s) * 64 + lane) * 3;  // max 6143 < 32768
        tsf[base]     = e0[s];
        tsf[base + 1] = e1[s];
        tsf[base + 2] = e2[s];
    }
    __syncthreads();

    // 2 waves merge: thread tid<128 owns source bid*128 + tid.
    if (tid < 128) {
        int l = tid & 63, srow = tid >> 6;
        int base0 = ((0 * 2 + srow) * 64 + l) * 3;
        float a0 = tsf[base0], a1 = tsf[base0 + 1], a2 = tsf[base0 + 2];
        #pragma unroll
        for (int w = 1; w < NWAVES; ++w) {
            int bse = ((w * 2 + srow) * 64 + l) * 3;
            merge33(tsf[bse], tsf[bse + 1], tsf[bse + 2], a0, a1, a2);
        }
        const float* sp = src + ((size_t)bid * SRC_PER_BLOCK + tid) * 3;
        float sx = sp[0], sy = sp[1], sz = sp[2];
        bool valid = (sx != 0.f) || (sy != 0.f) || (sz != 0.f);
        float qq = sx * sx + sy * sy + sz * sz;  // deferred |s|^2
        float sv = valid ? (sqrtf(fmaxf(a0 + qq, 0.f)) + sqrtf(fmaxf(a1 + qq, 0.f)) +
                            sqrtf(fmaxf(a2 + qq, 0.f)))
                         : 0.f;
        float cv = valid ? 1.f : 0.f;
        for (int off = 32; off >= 1; off >>= 1) {
            sv += __shfl_down(sv, off);
            cv += __shfl_down(cv, off);
        }
        if (l == 0) {
            atomicAdd(&acc[b], sv);
            atomicAdd(&cnt[b], cv);
            __threadfence();
        }
    }
    __syncthreads();

    if (tid == 0) {
        unsigned t = atomicAdd(ticket, 1u);
        if (t == (unsigned)(NBLOCKS - 1)) {
            float loss = 0.f;
            #pragma unroll
            for (int bb = 0; bb < BATCH; ++bb) {
                float as = atomicAdd(&acc[bb], 0.f);
                float ac = atomicAdd(&cnt[bb], 0.f);
                loss += as / (ac * 3.0f);
            }
            out[0] = loss * (1.0f / BATCH);
        }
    }
}

extern "C" void kernel_launch(void* const* d_in, const int* in_sizes, int n_in,
                              void* d_out, int out_size, void* d_ws, size_t ws_size,
                              hipStream_t stream) {
    const float* src = (const float*)d_in[0];
    const float* tgt = (const float*)d_in[1];
    float* out = (float*)d_out;

    // ws header: [0,16) acc[4]; [16,32) cnt[4]; [32,36) ticket
    float* acc = (float*)d_ws;
    float* cnt = acc + 4;
    unsigned* ticket = (unsigned*)((char*)d_ws + 32);

    hipMemsetAsync(d_ws, 0, 64, stream);  // zero header (graph-capturable)
    knn_fused<<<dim3(NBLOCKS), 1024, 0, stream>>>(src, tgt, acc, cnt, ticket, out);
}